// Round 1
// baseline (185.802 us; speedup 1.0000x reference)
//
#include <hip/hip_runtime.h>

// MHA: B=2, T=2048, E=1024, H=16, Dh=64. bf16 MFMA pipeline, fp32 I/O.
// R12: k_attn rewritten — LDS-throughput + serial-load-latency were the bound
//      (MfmaUtil 13.5%, VALUBusy 25%, HBM 29%: no visible pipe saturated;
//      per-wave 18 ds_read_b128 per 262 KFLOP = 16.4 FLOP/LDS-byte).
//      (a) QBLK=32 q-rows/wave (2-wave blocks, 64-row q-tiles): ak/av frags
//          reused across two q n-tiles => 26 FLOP/LDS-byte (1.8x cut).
//      (b) K/V double-buffer + stage-ahead (T3-lite): issue gload_lds for
//          jt+1 into buf^1 before computing jt; one barrier per iter. Kills
//          the per-iteration vmcnt(0) serial latency.
//      (c) s_setprio(1) around MFMA clusters (T5, +4-7% attn measured).
//      k_conv_all / k_qkv / k_oproj unchanged (attribution).
#define B_ 2
#define T_ 2048
#define E_ 1024
#define H_ 16
#define DH 64

typedef unsigned short u16;
typedef unsigned int u32;
typedef __bf16 bf16x8 __attribute__((ext_vector_type(8)));
typedef float f32x4 __attribute__((ext_vector_type(4)));

__device__ __forceinline__ u16 f2bf(float f) {
  u32 u = __builtin_bit_cast(u32, f);
  u = u + 0x7FFFu + ((u >> 16) & 1u);
  return (u16)(u >> 16);
}
__device__ __forceinline__ bf16x8 ldfrag(const u16* p) { return *(const bf16x8*)p; }

__device__ __forceinline__ void gload_lds16(const u16* g, u16* l) {
  __builtin_amdgcn_global_load_lds((const __attribute__((address_space(1))) u32*)g,
                                   (__attribute__((address_space(3))) u32*)l, 16, 0, 0);
}

// ---- all input conversions in one kernel ----
__global__ __launch_bounds__(256) void k_conv_all(const float* __restrict__ x,
                                                  const float* __restrict__ Wq,
                                                  const float* __restrict__ Wk,
                                                  const float* __restrict__ Wv,
                                                  const float* __restrict__ wo_w,
                                                  u16* __restrict__ xb, u16* __restrict__ wT,
                                                  u16* __restrict__ woB) {
  __shared__ __align__(16) u16 Ls[64][68];
  const int t = threadIdx.x;
  const int bx = blockIdx.x;
  if (bx < 2048 || bx >= 2816) {  // plain cast, 8 elems/thread
    const float* src = (bx < 2048) ? x : wo_w;
    u16* dst = (bx < 2048) ? xb : woB;
    u32 i = (((bx < 2048) ? bx : (bx - 2816)) * 256u + t) * 8u;
    float4 a = *(const float4*)(src + i);
    float4 b = *(const float4*)(src + i + 4);
    uint4 v;
    v.x = (u32)f2bf(a.x) | ((u32)f2bf(a.y) << 16);
    v.y = (u32)f2bf(a.z) | ((u32)f2bf(a.w) << 16);
    v.z = (u32)f2bf(b.x) | ((u32)f2bf(b.y) << 16);
    v.w = (u32)f2bf(b.z) | ((u32)f2bf(b.w) << 16);
    *(uint4*)(dst + i) = v;
    return;
  }
  // Wq/Wk/Wv [H,E,Dh] fp32 -> [3][H,Dh,E] bf16 via LDS tile; Wq gets 0.125*log2e.
  const int idx = bx - 2048;
  const int e0 = (idx & 15) * 64;
  const int h = (idx >> 4) & 15;
  const int which = idx >> 8;
  const float* src = (which == 0) ? Wq : ((which == 1) ? Wk : Wv);
  const float scale = (which == 0) ? 0.18033688011112042f : 1.0f;
#pragma unroll
  for (int p = 0; p < 4; p++) {
    int id2 = p * 256 + t;
    int row = id2 >> 4, ch = id2 & 15;
    float4 v = *(const float4*)(src + ((size_t)h * E_ + e0 + row) * DH + ch * 4);
    uint2 pk;
    pk.x = (u32)f2bf(v.x * scale) | ((u32)f2bf(v.y * scale) << 16);
    pk.y = (u32)f2bf(v.z * scale) | ((u32)f2bf(v.w * scale) << 16);
    *(uint2*)(&Ls[row][ch * 4]) = pk;
  }
  __syncthreads();
  u16* dst = wT + ((size_t)which * H_ + h) * (DH * E_);
#pragma unroll
  for (int p = 0; p < 4; p++) {
    int id2 = p * 256 + t;
    int d = id2 >> 4, ec = id2 & 15;
    uint2 pk;
    pk.x = (u32)Ls[ec * 4 + 0][d] | ((u32)Ls[ec * 4 + 1][d] << 16);
    pk.y = (u32)Ls[ec * 4 + 2][d] | ((u32)Ls[ec * 4 + 3][d] << 16);
    *(uint2*)(dst + (size_t)d * E_ + e0 + ec * 4) = pk;
  }
}

// ---- fused QKV GEMM: C[4096,3072] = X[4096,1024] * W^T (W as [3072][1024] bf16) ----
__global__ __launch_bounds__(256, 3) void k_qkv(const u16* __restrict__ xb, const u16* __restrict__ wT,
                                                u16* __restrict__ Qb, u16* __restrict__ Kb,
                                                u16* __restrict__ VbT) {
  __shared__ __align__(16) u16 As[128 * 64];
  __shared__ __align__(16) u16 Bs[128 * 64];
  const int tid = threadIdx.x;
  const int w = tid >> 6, lane = tid & 63, quad = lane >> 4, lr = lane & 15;
  const int wr = w >> 1, wc = w & 1;
  const int t0 = blockIdx.x * 128;
  const int n0 = blockIdx.y * 128;
  const int sr = lane >> 3, sc = lane & 7;

  f32x4 acc[4][4];
  const f32x4 z4 = {0.f, 0.f, 0.f, 0.f};
#pragma unroll
  for (int i = 0; i < 4; i++)
#pragma unroll
    for (int j = 0; j < 4; j++) acc[i][j] = z4;

  for (int k0 = 0; k0 < E_; k0 += 64) {
    __syncthreads();
#pragma unroll
    for (int ii = 0; ii < 4; ii++) {
      int ra = w * 32 + ii * 8 + sr;
      gload_lds16(xb + (size_t)(t0 + ra) * E_ + k0 + ((sc ^ (ra & 7)) << 3),
                  As + (w * 32 + ii * 8) * 64);
      gload_lds16(wT + (size_t)(n0 + ra) * E_ + k0 + ((sc ^ (ra & 7)) << 3),
                  Bs + (w * 32 + ii * 8) * 64);
    }
    __syncthreads();
#pragma unroll
    for (int kk = 0; kk < 2; kk++) {
      bf16x8 af[4], bfv[4];
#pragma unroll
      for (int rt = 0; rt < 4; rt++) {
        int row = wr * 64 + rt * 16 + lr;
        af[rt] = ldfrag(As + row * 64 + (((kk * 4 + quad) ^ (row & 7)) << 3));
      }
#pragma unroll
      for (int ct = 0; ct < 4; ct++) {
        int row = wc * 64 + ct * 16 + lr;
        bfv[ct] = ldfrag(Bs + row * 64 + (((kk * 4 + quad) ^ (row & 7)) << 3));
      }
#pragma unroll
      for (int rt = 0; rt < 4; rt++)
#pragma unroll
        for (int ct = 0; ct < 4; ct++)
          acc[rt][ct] = __builtin_amdgcn_mfma_f32_16x16x32_bf16(af[rt], bfv[ct], acc[rt][ct], 0, 0, 0);
    }
  }

  const int qkv = n0 >> 10;
  if (qkv < 2) {
    u16* outp = (qkv == 0) ? Qb : Kb;
#pragma unroll
    for (int rt = 0; rt < 4; rt++)
#pragma unroll
      for (int ct = 0; ct < 4; ct++) {
        int n = n0 + wc * 64 + ct * 16 + lr;
        int h = (n >> 6) & 15, d = n & 63;
#pragma unroll
        for (int r = 0; r < 4; r++) {
          int t = t0 + wr * 64 + rt * 16 + quad * 4 + r;
          int bb = t >> 11, tt = t & 2047;
          outp[(((size_t)bb * H_ + h) * T_ + tt) * DH + d] = f2bf(acc[rt][ct][r]);
        }
      }
  } else {
#pragma unroll
    for (int rt = 0; rt < 4; rt++)
#pragma unroll
      for (int ct = 0; ct < 4; ct++) {
        int n = n0 + wc * 64 + ct * 16 + lr;
        int h = (n >> 6) & 15, d = n & 63;
        int t = t0 + wr * 64 + rt * 16 + quad * 4;
        int bb = t >> 11, tt = t & 2047;
        uint2 pk;
        pk.x = (u32)f2bf(acc[rt][ct][0]) | ((u32)f2bf(acc[rt][ct][1]) << 16);
        pk.y = (u32)f2bf(acc[rt][ct][2]) | ((u32)f2bf(acc[rt][ct][3]) << 16);
        *(uint2*)(VbT + (((size_t)bb * H_ + h) * DH + d) * T_ + tt) = pk;
      }
  }
}

// ---- full-K flash attention: 2 waves x 32 q-rows, K/V double-buffered ----
// block (i,h,bb): i in [0,16). q-tiles (31-i) then (i), 64 rows each, over all
// their 64-row KV tiles (33 total, balanced). Stage-ahead: gload_lds for tile
// jt+1 -> buf^1 issued before computing jt; single barrier per iteration.
// Each wave owns 32 q-rows (two 16-row n-tiles) so each K/V LDS frag feeds
// 2 MFMAs. p = exp2(s - 20) fixed-max softmax (uniform scale divides out).
__global__ __launch_bounds__(128, 1) void k_attn(const u16* __restrict__ Qb, const u16* __restrict__ Kb,
                                                 const u16* __restrict__ VbT, u16* __restrict__ AO) {
  __shared__ __align__(16) u16 Ks[2][4096];   // K tiles 64x64, double-buffered
  __shared__ __align__(16) u16 Vts[2][4096];  // V^T tiles 64x64, double-buffered
  __shared__ __align__(16) u16 Ps[4096];      // P [q 64][s 64], wave-private rows
  const int tid = threadIdx.x;
  const int w = tid >> 6, lane = tid & 63, quad = lane >> 4, lr = lane & 15;
  const int l7 = lr & 7;
  const int srow = lane >> 3, schunk = lane & 7;
  const int i = blockIdx.x;  // [0,16): pair (31-i, i)
  const int h = blockIdx.y, bb = blockIdx.z;
  const u16* qb = Qb + ((size_t)bb * H_ + h) * (size_t)(T_ * DH);
  const u16* kb = Kb + ((size_t)bb * H_ + h) * (size_t)(T_ * DH);
  const u16* vbT = VbT + ((size_t)bb * H_ + h) * (size_t)(T_ * DH);  // [DH][T]
  const f32x4 z4 = {0.f, 0.f, 0.f, 0.f};
  const float MFIX = 20.0f;

  for (int jb = 0; jb < 2; jb++) {
    const int qt = jb ? i : (31 - i);
    const int t0 = qt * 64;

    // Q B-frags (pre-scaled 0.125*log2e): rows w*32 + nt*16 + lr
    bf16x8 bq[2][2];
#pragma unroll
    for (int nt = 0; nt < 2; nt++) {
      const u16* qrow = qb + (size_t)(t0 + w * 32 + nt * 16 + lr) * DH;
      bq[nt][0] = ldfrag(qrow + quad * 8);
      bq[nt][1] = ldfrag(qrow + 32 + quad * 8);
    }

    f32x4 o_acc[4][2];
#pragma unroll
    for (int dt = 0; dt < 4; dt++) {
      o_acc[dt][0] = z4;
      o_acc[dt][1] = z4;
    }
    float l_i[2] = {0.f, 0.f};

    // prologue: stage KV tile 0 into buffer 0 (8 rows/wave per round)
#pragma unroll
    for (int ii = 0; ii < 4; ii++) {
      int r = ii * 16 + w * 8 + srow;
      gload_lds16(kb + (size_t)r * DH + ((schunk ^ (r & 7)) << 3),
                  &Ks[0][(ii * 16 + w * 8) * 64]);
      gload_lds16(vbT + (size_t)r * T_ + ((schunk ^ (r & 7)) << 3),
                  &Vts[0][(ii * 16 + w * 8) * 64]);
    }
    __syncthreads();

    int cur = 0;
    for (int jt = 0; jt <= qt; jt++) {
      const int j0 = jt * 64;
      if (jt < qt) {  // async stage next KV tile into the other buffer
        const int jn = j0 + 64;
#pragma unroll
        for (int ii = 0; ii < 4; ii++) {
          int r = ii * 16 + w * 8 + srow;
          gload_lds16(kb + (size_t)(jn + r) * DH + ((schunk ^ (r & 7)) << 3),
                      &Ks[cur ^ 1][(ii * 16 + w * 8) * 64]);
          gload_lds16(vbT + (size_t)r * T_ + jn + ((schunk ^ (r & 7)) << 3),
                      &Vts[cur ^ 1][(ii * 16 + w * 8) * 64]);
        }
      }

      // St = K·Q^T : D[m=s][n=q], ak frags reused across both q n-tiles
      f32x4 s_acc[4][2];
#pragma unroll
      for (int st = 0; st < 4; st++) {
        s_acc[st][0] = z4;
        s_acc[st][1] = z4;
      }
      __builtin_amdgcn_s_setprio(1);
#pragma unroll
      for (int st = 0; st < 4; st++) {
        bf16x8 ak0 = ldfrag(&Ks[cur][(st * 16 + lr) * 64 + ((quad ^ l7) << 3)]);
        bf16x8 ak1 = ldfrag(&Ks[cur][(st * 16 + lr) * 64 + (((4 + quad) ^ l7) << 3)]);
#pragma unroll
        for (int nt = 0; nt < 2; nt++) {
          s_acc[st][nt] = __builtin_amdgcn_mfma_f32_16x16x32_bf16(ak0, bq[nt][0], s_acc[st][nt], 0, 0, 0);
          s_acc[st][nt] = __builtin_amdgcn_mfma_f32_16x16x32_bf16(ak1, bq[nt][1], s_acc[st][nt], 0, 0, 0);
        }
      }
      __builtin_amdgcn_s_setprio(0);

      if (jt == qt) {  // diagonal: mask s_loc > q_loc
#pragma unroll
        for (int nt = 0; nt < 2; nt++) {
          int qloc = w * 32 + nt * 16 + lr;
#pragma unroll
          for (int st = 0; st < 4; st++) {
            int sbase = st * 16 + quad * 4;
#pragma unroll
            for (int r = 0; r < 4; r++)
              if (sbase + r > qloc) s_acc[st][nt][r] = -__builtin_inff();
          }
        }
      }

      // fixed-max: p = exp2(s - 20); accumulate per-lane partial l
#pragma unroll
      for (int nt = 0; nt < 2; nt++) {
        float rsum = 0.f;
#pragma unroll
        for (int st = 0; st < 4; st++) {
          float p0 = __builtin_amdgcn_exp2f(s_acc[st][nt][0] - MFIX);
          float p1 = __builtin_amdgcn_exp2f(s_acc[st][nt][1] - MFIX);
          float p2 = __builtin_amdgcn_exp2f(s_acc[st][nt][2] - MFIX);
          float p3 = __builtin_amdgcn_exp2f(s_acc[st][nt][3] - MFIX);
          rsum += (p0 + p1) + (p2 + p3);
          uint2 pk;  // truncating bf16 pack
          pk.x = (__builtin_bit_cast(u32, p0) >> 16) | (__builtin_bit_cast(u32, p1) & 0xffff0000u);
          pk.y = (__builtin_bit_cast(u32, p2) >> 16) | (__builtin_bit_cast(u32, p3) & 0xffff0000u);
          *(uint2*)(Ps + (w * 32 + nt * 16 + lr) * 64 +
                    (((st * 2 + (quad >> 1)) ^ l7) << 3) + ((quad & 1) << 2)) = pk;
        }
        l_i[nt] += rsum;
      }

      // O^T += V^T · P (P rows written by the same wave: in-order DS pipe);
      // av frags reused across both q n-tiles
      __builtin_amdgcn_s_setprio(1);
#pragma unroll
      for (int kk = 0; kk < 2; kk++) {
        bf16x8 bp0 = ldfrag(Ps + (w * 32 + lr) * 64 + (((kk * 4 + quad) ^ l7) << 3));
        bf16x8 bp1 = ldfrag(Ps + (w * 32 + 16 + lr) * 64 + (((kk * 4 + quad) ^ l7) << 3));
#pragma unroll
        for (int dt = 0; dt < 4; dt++) {
          bf16x8 av = ldfrag(&Vts[cur][(dt * 16 + lr) * 64 + (((kk * 4 + quad) ^ l7) << 3)]);
          o_acc[dt][0] = __builtin_amdgcn_mfma_f32_16x16x32_bf16(av, bp0, o_acc[dt][0], 0, 0, 0);
          o_acc[dt][1] = __builtin_amdgcn_mfma_f32_16x16x32_bf16(av, bp1, o_acc[dt][1], 0, 0, 0);
        }
      }
      __builtin_amdgcn_s_setprio(0);

      __syncthreads();  // drains lgkm (reads of buf[cur]) + vm (stage of buf^1)
      cur ^= 1;
    }

    // cross-quad l reduction (lanes ^16, ^32 share the same q), normalize, store
#pragma unroll
    for (int nt = 0; nt < 2; nt++) {
      float l = l_i[nt];
      l += __shfl_xor(l, 16);
      l += __shfl_xor(l, 32);
      float inv = 1.0f / l;
      int t = t0 + w * 32 + nt * 16 + lr;
      u16* orow = AO + ((size_t)bb * T_ + t) * E_ + h * DH;
#pragma unroll
      for (int dt = 0; dt < 4; dt++) {
        uint2 pk;
        pk.x = (u32)f2bf(o_acc[dt][nt][0] * inv) | ((u32)f2bf(o_acc[dt][nt][1] * inv) << 16);
        pk.y = (u32)f2bf(o_acc[dt][nt][2] * inv) | ((u32)f2bf(o_acc[dt][nt][3] * inv) << 16);
        *(uint2*)(orow + dt * 16 + quad * 4) = pk;
      }
    }
  }
}

// ---- output projection, 64x64 tiles (grid 1024 = 4/CU): out = AO @ wo^T + b ----
__global__ __launch_bounds__(256, 4) void k_oproj(const u16* __restrict__ AO, const u16* __restrict__ woB,
                                                  const float* __restrict__ bias, float* __restrict__ out) {
  __shared__ __align__(16) u16 As[64 * 64];  // 8 KB
  __shared__ __align__(16) u16 Bs[64 * 64];  // 8 KB
  const int tid = threadIdx.x;
  const int w = tid >> 6, lane = tid & 63, quad = lane >> 4, lr = lane & 15;
  const int r0 = blockIdx.x * 64, n0 = blockIdx.y * 64;
  const int sr = lane >> 3, sc = lane & 7;

  f32x4 acc[4];
  const f32x4 z4 = {0.f, 0.f, 0.f, 0.f};
#pragma unroll
  for (int i = 0; i < 4; i++) acc[i] = z4;

  for (int k0 = 0; k0 < E_; k0 += 64) {
    __syncthreads();
#pragma unroll
    for (int ii = 0; ii < 2; ii++) {  // A + B: wave w stages rows w*16..+15 of each
      int ra = w * 16 + ii * 8 + sr;
      gload_lds16(AO + (size_t)(r0 + ra) * E_ + k0 + ((sc ^ (ra & 7)) << 3),
                  As + (w * 16 + ii * 8) * 64);
      gload_lds16(woB + (size_t)(n0 + ra) * E_ + k0 + ((sc ^ (ra & 7)) << 3),
                  Bs + (w * 16 + ii * 8) * 64);
    }
    __syncthreads();
#pragma unroll
    for (int kk = 0; kk < 2; kk++) {
      bf16x8 af[4], bfv;
#pragma unroll
      for (int rt = 0; rt < 4; rt++) {
        int row = rt * 16 + lr;
        af[rt] = ldfrag(As + row * 64 + (((kk * 4 + quad) ^ (row & 7)) << 3));
      }
      {
        int row = w * 16 + lr;
        bfv = ldfrag(Bs + row * 64 + (((kk * 4 + quad) ^ (row & 7)) << 3));
      }
#pragma unroll
      for (int rt = 0; rt < 4; rt++)
        acc[rt] = __builtin_amdgcn_mfma_f32_16x16x32_bf16(af[rt], bfv, acc[rt], 0, 0, 0);
    }
  }

  {
    int col = n0 + w * 16 + lr;
    float bv = bias[col];
#pragma unroll
    for (int rt = 0; rt < 4; rt++)
#pragma unroll
      for (int r = 0; r < 4; r++) {
        int row = r0 + rt * 16 + quad * 4 + r;
        out[(size_t)row * E_ + col] = acc[rt][r] + bv;
      }
  }
}

extern "C" void kernel_launch(void* const* d_in, const int* in_sizes, int n_in,
                              void* d_out, int out_size, void* d_ws, size_t ws_size,
                              hipStream_t stream) {
  const float* x = (const float*)d_in[0];
  const float* Wq = (const float*)d_in[1];
  const float* Wk = (const float*)d_in[2];
  const float* Wv = (const float*)d_in[3];
  const float* wo_w = (const float*)d_in[4];
  const float* wo_b = (const float*)d_in[5];
  float* out = (float*)d_out;
  char* ws = (char*)d_ws;

  u16* xb  = (u16*)(ws + 0);          //  8 MiB: x bf16 [B,T,E]
  u16* wT  = (u16*)(ws + 8388608);    //  6 MiB: [3][H,Dh,E] bf16
  u16* woB = (u16*)(ws + 14680064);   //  2 MiB: wo bf16 [E,E]
  u16* Qb  = (u16*)(ws + 16777216);   //  8 MiB: Q [B,H,T,Dh] (pre-scaled 0.125*log2e)
  u16* Kb  = (u16*)(ws + 25165824);   //  8 MiB: K [B,H,T,Dh]
  u16* VbT = (u16*)(ws + 33554432);   //  8 MiB: V^T [B,H,Dh,T]
  u16* AO  = (u16*)(ws + 41943040);   //  8 MiB: attn out bf16 [B,T,E]

  k_conv_all<<<3328, 256, 0, stream>>>(x, Wq, Wk, Wv, wo_w, xb, wT, woB);
  k_qkv<<<dim3(32, 24), 256, 0, stream>>>(xb, wT, Qb, Kb, VbT);
  k_attn<<<dim3(16, 16, 2), 128, 0, stream>>>(Qb, Kb, VbT, AO);
  k_oproj<<<dim3(64, 16), 256, 0, stream>>>(AO, woB, wo_b, out);
}